// Round 3
// baseline (199.408 us; speedup 1.0000x reference)
//
#include <hip/hip_runtime.h>
#include <math.h>

// Router: scores = x @ emb^T [32768 x 64] fp32, top-2 + 2-way softmax scatter.
//
// lane = TOKEN (64 tokens/block), wave w owns experts [16w,16w+16).
// emb streams through the SCALAR pipe (wave-uniform address -> s_load_dwordx16,
// v_fmac with SGPR operand) -> zero LDS traffic for emb.
// x staged via global_load_lds (linear dest, XOR-pre-swizzled source) and read
// lane-varying: 16 ds_read_b128 per wave-chunk, 64 FMAs per read.
// Round-2 was LDS-return-BW-bound (272 broadcast b128/wave-chunk @ ~12cyc);
// this cuts LDS reads 17x and moves the streamed operand to the scalar pipe.

constexpr int HDIM = 1024;
constexpr int NEXP = 64;
constexpr int TPB  = 64;            // tokens per block
constexpr int BK   = 64;            // k per chunk
constexpr int NQ   = BK / 4;        // 16 quads
constexpr int NTHREADS = 256;
constexpr int NCHUNK = HDIM / BK;   // 16

__global__ __launch_bounds__(NTHREADS, 2)
void router_kernel(const float* __restrict__ x,
                   const float* __restrict__ emb,
                   float* __restrict__ out)
{
    __shared__ float4 xs[2][TPB][NQ];   // 32 KiB, x[token][quad^(token&15)]
    __shared__ float4 cand[4][TPB];     // 4 KiB, per-wave top-2 candidates

    const int tid  = threadIdx.x;
    const int lane = tid & 63;                                   // token-in-block
    const int w    = __builtin_amdgcn_readfirstlane(tid >> 6);   // expert group (SGPR)
    const int tok0 = blockIdx.x * TPB;
    const int sw   = lane & 15;

    // Stage chunk C of x into buffer P. Dest is wave-linear (base + lane*16);
    // the read-side XOR swizzle is folded into the per-lane GLOBAL source.
#define STAGE(P, C)                                                            \
    do {                                                                       \
        _Pragma("unroll")                                                      \
        for (int j = 0; j < 4; ++j) {                                          \
            const int g = j * 256 + tid;                                       \
            const int r = g >> 4, q = g & 15;                                  \
            const float* src = x + (size_t)(tok0 + r) * HDIM + (C) * BK        \
                                 + ((q ^ (r & 15)) * 4);                       \
            __builtin_amdgcn_global_load_lds(                                  \
                (const __attribute__((address_space(1))) void*)src,            \
                (__attribute__((address_space(3))) void*)&xs[P][r][q],         \
                16, 0, 0);                                                     \
        }                                                                      \
    } while (0)

    float acc[16];
#pragma unroll
    for (int i = 0; i < 16; ++i) acc[i] = 0.f;

    STAGE(0, 0);
    int p = 0;

#pragma unroll 1
    for (int c = 0; c < NCHUNK; ++c) {
        __syncthreads();                       // chunk c staged (vmcnt drained)
        if (c + 1 < NCHUNK) STAGE(p ^ 1, c + 1);

#pragma unroll
        for (int kb = 0; kb < 4; ++kb) {
            // this lane's token: 16 k-values into regs (4 swizzled b128 reads)
            float4 xq[4];
#pragma unroll
            for (int i = 0; i < 4; ++i) xq[i] = xs[p][lane][(4 * kb + i) ^ sw];
            const float* xf = (const float*)xq;

#pragma unroll
            for (int e = 0; e < 16; ++e) {
                // fully uniform address -> s_load_dwordx16; SGPR operand FMAs
                const float* ep = emb + (size_t)(16 * w + e) * HDIM
                                      + c * BK + kb * 16;
#pragma unroll
                for (int i = 0; i < 16; ++i)
                    acc[e] = fmaf(ep[i], xf[i], acc[e]);
            }
        }
        p ^= 1;
    }

    // ---- per-lane local top-2 over this wave's 16 experts (register-only) ----
    float v1 = acc[0], v2 = -INFINITY;
    int   j1 = 0,      j2 = 0;
#pragma unroll
    for (int j = 1; j < 16; ++j) {
        if (acc[j] > v1)      { v2 = v1; j2 = j1; v1 = acc[j]; j1 = j; }
        else if (acc[j] > v2) { v2 = acc[j]; j2 = j; }
    }
    float4 cd;
    cd.x = v1; cd.y = __int_as_float(16 * w + j1);
    cd.z = v2; cd.w = __int_as_float(16 * w + j2);
    cand[w][lane] = cd;
    __syncthreads();

    // ---- merge 4 waves' candidates, ascending expert order (tie: lowest idx) ----
    float V1 = -INFINITY, V2 = -INFINITY;
    int   E1 = 0,         E2 = 0;
#pragma unroll
    for (int ww = 0; ww < 4; ++ww) {
        const float4 q = cand[ww][lane];
        const float a = q.x; const int ea = __float_as_int(q.y);
        const float b = q.z; const int eb = __float_as_int(q.w);
        if (a > V1)      { V2 = V1; E2 = E1; V1 = a; E1 = ea; }
        else if (a > V2) { V2 = a; E2 = ea; }
        if (b > V1)      { V2 = V1; E2 = E1; V1 = b; E1 = eb; }
        else if (b > V2) { V2 = b; E2 = eb; }
    }
    const float et = expf(V2 - V1);
    const float p1 = 1.f / (1.f + et);
    const float p2 = et / (1.f + et);

    // ---- build output rows in LDS (reuse xs[0]), then coalesced store ----
    float4* rb = (float4*)&xs[0][0][0];        // [64 tokens][16 quads], swizzled
#pragma unroll
    for (int qq = 0; qq < 4; ++qq) {
        const int q = 4 * w + qq;              // quad = experts 4q..4q+3
        float4 o;
        float* of = (float*)&o;
#pragma unroll
        for (int i = 0; i < 4; ++i) {
            const int e = 4 * q + i;
            of[i] = (e == E1) ? p1 : (e == E2) ? p2 : 0.f;
        }
        rb[lane * 16 + (q ^ sw)] = o;
    }
    __syncthreads();

    const int t  = tid >> 2;
    const int qb = (tid & 3) * 4;
#pragma unroll
    for (int i = 0; i < 4; ++i) {
        const int q = qb + i;
        const float4 o = rb[t * 16 + (q ^ (t & 15))];
        *(float4*)(out + (size_t)(tok0 + t) * NEXP + q * 4) = o;
    }
#undef STAGE
}

extern "C" void kernel_launch(void* const* d_in, const int* in_sizes, int n_in,
                              void* d_out, int out_size, void* d_ws, size_t ws_size,
                              hipStream_t stream)
{
    const float* x   = (const float*)d_in[0];
    const float* emb = (const float*)d_in[1];
    float* out = (float*)d_out;

    const int n_tokens = in_sizes[0] / HDIM;     // 32768
    const int nblocks  = n_tokens / TPB;         // 512

    router_kernel<<<nblocks, NTHREADS, 0, stream>>>(x, emb, out);
}